// Round 1
// baseline (1370.829 us; speedup 1.0000x reference)
//
#include <hip/hip_runtime.h>

// Conv2D 3x3 VALID stride 1, fp32 direct convolution, register-tiled.
// x: (32, 64, 112, 112)  w: (128, 64, 3, 3)  bias: (128)  out: (32, 128, 110, 110)
//
// Mapping: thread = 1 output pixel x 16 output channels.
//   blockIdx.x * 256 + tid -> flat pixel p = ((n*110)+oh)*110 + ow
//   blockIdx.y             -> co group (8 groups of TCO=16)
// Weights are read with block-uniform indices -> compiler scalarizes to s_load,
// FMA takes the weight as an SGPR operand (1 sgpr read per VALU op is legal).
// x reads: consecutive threads = consecutive ow -> coalesced row segments.

#define CIN   64
#define COUT  128
#define INH   112
#define INW   112
#define OUTH  110
#define OUTW  110
#define NBATCH 32
#define TCO   16
#define NPIX  (NBATCH * OUTH * OUTW)

__global__ __launch_bounds__(256) void SimpleConv2D_kernel(
    const float* __restrict__ x,
    const float* __restrict__ w,
    const float* __restrict__ bias,
    float* __restrict__ out)
{
    int p = blockIdx.x * 256 + threadIdx.x;
    const int co0 = blockIdx.y * TCO;
    const bool valid = p < NPIX;
    if (!valid) p = 0;  // clamp: loads stay in-bounds, stores are skipped

    const int n   = p / (OUTH * OUTW);
    const int rem = p - n * (OUTH * OUTW);
    const int oh  = rem / OUTW;
    const int ow  = rem - oh * OUTW;

    float acc[TCO];
#pragma unroll
    for (int t = 0; t < TCO; ++t) acc[t] = bias[co0 + t];

    // x base at (n, ci=0, oh, ow)
    const float* xb = x + ((size_t)n * CIN) * (INH * INW) + (size_t)oh * INW + ow;
    // w base at (co0, ci=0, 0, 0)
    const float* wb = w + (size_t)co0 * CIN * 9;

    for (int ci = 0; ci < CIN; ++ci) {
        const float* xp = xb + (size_t)ci * (INH * INW);
        const float* wp = wb + ci * 9;
#pragma unroll
        for (int kh = 0; kh < 3; ++kh) {
            const float x0 = xp[kh * INW + 0];
            const float x1 = xp[kh * INW + 1];
            const float x2 = xp[kh * INW + 2];
#pragma unroll
            for (int t = 0; t < TCO; ++t) {
                const float* wt = wp + t * (CIN * 9) + kh * 3;  // block-uniform address
                acc[t] = fmaf(x0, wt[0], acc[t]);
                acc[t] = fmaf(x1, wt[1], acc[t]);
                acc[t] = fmaf(x2, wt[2], acc[t]);
            }
        }
    }

    if (valid) {
        const size_t ob = ((size_t)n * COUT + co0) * (OUTH * OUTW) + (size_t)oh * OUTW + ow;
#pragma unroll
        for (int t = 0; t < TCO; ++t)
            out[ob + (size_t)t * (OUTH * OUTW)] = acc[t];
    }
}

extern "C" void kernel_launch(void* const* d_in, const int* in_sizes, int n_in,
                              void* d_out, int out_size, void* d_ws, size_t ws_size,
                              hipStream_t stream) {
    const float* x    = (const float*)d_in[0];
    const float* w    = (const float*)d_in[1];
    const float* bias = (const float*)d_in[2];
    float* out        = (float*)d_out;

    dim3 grid((NPIX + 255) / 256, COUT / TCO);
    SimpleConv2D_kernel<<<grid, dim3(256), 0, stream>>>(x, w, bias, out);
}

// Round 2
// 369.974 us; speedup vs baseline: 3.7052x; 3.7052x over previous
//
#include <hip/hip_runtime.h>
#include <hip/hip_bf16.h>

// Implicit-GEMM conv2d 3x3 VALID, stride 1, via bf16 MFMA.
// x: (32,64,112,112) f32  w: (128,64,3,3) f32  bias: (128)  out: (32,128,110,110) f32
// GEMM view: M=Cout=128, K=(kh,kw,ci)=576, N=pixels. Per block: one (n,oh) row,
// tile 128co x 128px (110 valid). K-loop has NO barriers: A frags from L2,
// B frags from LDS (staged once per block).

#define CIN   64
#define COUT  128
#define INH   112
#define INW   112
#define OUTH  110
#define OUTW  110
#define NB    32
#define KTOT  576           // k = (kh*3+kw)*64 + ci
#define NPIX  (NB*OUTH*OUTW)

typedef __attribute__((ext_vector_type(8))) short short8;     // 8 bf16 (4 VGPRs)
typedef __attribute__((ext_vector_type(4))) float f32x4;
typedef __attribute__((ext_vector_type(4))) unsigned int uint4v;

static __device__ __forceinline__ unsigned short f2bf(float f) {
    union { float f; unsigned int u; } v; v.f = f;
    return (unsigned short)((v.u + 0x7FFF + ((v.u >> 16) & 1)) >> 16);  // RNE
}

// ---------- pre-pass 1: x NCHW f32 -> NHWC bf16 (into d_ws) ----------
__global__ __launch_bounds__(256) void convert_x(const float* __restrict__ x,
                                                 unsigned short* __restrict__ xhwc) {
    __shared__ unsigned short lds[64 * 117];      // pitch 117: conflict-free transpose
    const int h = blockIdx.x;                     // 0..111
    const int n = blockIdx.y;                     // 0..31
    const int t = threadIdx.x;
    const float* xp = x + ((size_t)n * CIN) * (INH * INW) + (size_t)h * INW;
#pragma unroll
    for (int i = 0; i < 28; ++i) {                // 64ci x 112w = 7168 floats
        int f = t + 256 * i;
        int ci = f / 112, w = f - ci * 112;
        lds[ci * 117 + w] = f2bf(xp[(size_t)ci * (INH * INW) + w]);
    }
    __syncthreads();
    unsigned int* dst = (unsigned int*)(xhwc + ((size_t)(n * INH + h) * INW) * 64);
#pragma unroll
    for (int i = 0; i < 14; ++i) {                // 3584 dwords out, fully coalesced
        int g = t + 256 * i;
        int w = g >> 5, cp = g & 31;
        unsigned int lo = lds[(cp * 2) * 117 + w];
        unsigned int hi = lds[(cp * 2 + 1) * 117 + w];
        dst[g] = lo | (hi << 16);
    }
}

// ---------- pre-pass 2: weights -> bf16, fragment-major A_packed ----------
// A_packed halfword index: ((k>>3)*128 + m)*8 + (k&7), k=(kh*3+kw)*64+ci
__global__ __launch_bounds__(256) void prepack_w(const float* __restrict__ w,
                                                 unsigned short* __restrict__ ap) {
    int flat = blockIdx.x * 256 + threadIdx.x;    // 128*576 = 73728 exactly
    int m = flat / KTOT;
    int k = flat - m * KTOT;
    int khw = k >> 6, ci = k & 63;
    int kh = khw / 3, kw = khw - kh * 3;
    float v = w[((m * CIN + ci) * 3 + kh) * 3 + kw];
    ap[((k >> 3) * COUT + m) * 8 + (k & 7)] = f2bf(v);
}

// ---------- main GEMM ----------
__global__ __launch_bounds__(256) void conv_gemm(const unsigned short* __restrict__ xhwc,
                                                 const unsigned short* __restrict__ ap,
                                                 const float* __restrict__ bias,
                                                 float* __restrict__ out) {
    // B tile: 3 input rows (oh..oh+2), per-w cell padded 64->72 halfwords
    // (lane stride 144B = 36 dwords -> only 2-way bank aliasing = free).
    // +slack so garbage-column frag reads (ow>=110) never go OOB.
    __shared__ unsigned short ldsB[25600];        // 51.2 KB -> 3 blocks/CU
    const int oh = blockIdx.x;                    // 0..109
    const int n  = blockIdx.y;                    // 0..31
    const int t  = threadIdx.x;

    {   // stage B: 3 contiguous rows of xhwc = 2688 uint4
        const uint4v* src = (const uint4v*)(xhwc + ((size_t)(n * INH + oh) * INW) * 64);
        for (int c = t; c < 2688; c += 256) {
            int kh = c / 896;                      // 896 = 112w * 8 parts
            int r  = c - kh * 896;
            int w_ = r >> 3, part = r & 7;
            *(uint4v*)&ldsB[(kh * INW + w_) * 72 + part * 8] = src[c];
        }
    }
    __syncthreads();   // the ONLY barrier

    const int lane = t & 63;
    const int wave = t >> 6;
    const int m_base  = (wave >> 1) * 64;          // co half
    const int px_base = (wave & 1) * 64;           // px half
    const int l16  = lane & 15;
    const int quad = lane >> 4;                    // 0..3

    f32x4 acc[4][4] = {};                          // [m-tile][n-tile]
    const short8* A = (const short8*)ap;           // index kb*128 + m

    for (int kc = 0; kc < 18; ++kc) {              // K chunks of 32
        const int khw = kc >> 1;
        const int kh = khw / 3, kw = khw - kh * 3; // uniform
        const int ci0 = (kc & 1) * 32 + quad * 8;
        short8 a[4], b[4];
#pragma unroll
        for (int i = 0; i < 4; ++i)                // A frag: lane k-run = k&7 contiguous
            a[i] = A[(kc * 4 + quad) * COUT + (m_base + i * 16 + l16)];
#pragma unroll
        for (int j = 0; j < 4; ++j) {              // B frag: 8 consecutive ci = b128
            int ow = px_base + j * 16 + l16;
            b[j] = *(const short8*)&ldsB[(kh * INW + ow + kw) * 72 + ci0];
        }
#pragma unroll
        for (int i = 0; i < 4; ++i)
#pragma unroll
            for (int j = 0; j < 4; ++j)
                acc[i][j] = __builtin_amdgcn_mfma_f32_16x16x32_bf16(a[i], b[j], acc[i][j], 0, 0, 0);
    }

    // C/D layout (verified m89): col = lane&15 -> ow, row = quad*4 + reg -> co
#pragma unroll
    for (int i = 0; i < 4; ++i) {
        const int co = m_base + i * 16 + quad * 4;
#pragma unroll
        for (int j = 0; j < 4; ++j) {
            const int ow = px_base + j * 16 + l16;
            if (ow < OUTW) {
                const size_t ob = (((size_t)n * COUT + co) * OUTH + oh) * OUTW + ow;
#pragma unroll
                for (int r = 0; r < 4; ++r)
                    out[ob + (size_t)r * (OUTH * OUTW)] = acc[i][j][r] + bias[co + r];
            }
        }
    }
}

// ---------- fallback (round-1 direct conv) if ws too small ----------
#define TCO 16
__global__ __launch_bounds__(256) void conv_direct(const float* __restrict__ x,
                                                   const float* __restrict__ w,
                                                   const float* __restrict__ bias,
                                                   float* __restrict__ out) {
    int p = blockIdx.x * 256 + threadIdx.x;
    const int co0 = blockIdx.y * TCO;
    const bool valid = p < NPIX;
    if (!valid) p = 0;
    const int n = p / (OUTH * OUTW);
    const int rem = p - n * (OUTH * OUTW);
    const int oh = rem / OUTW;
    const int ow = rem - oh * OUTW;
    float acc[TCO];
#pragma unroll
    for (int t = 0; t < TCO; ++t) acc[t] = bias[co0 + t];
    const float* xb = x + ((size_t)n * CIN) * (INH * INW) + (size_t)oh * INW + ow;
    const float* wb = w + (size_t)co0 * CIN * 9;
    for (int ci = 0; ci < CIN; ++ci) {
        const float* xp = xb + (size_t)ci * (INH * INW);
        const float* wp = wb + ci * 9;
#pragma unroll
        for (int kh = 0; kh < 3; ++kh) {
            const float x0 = xp[kh * INW + 0];
            const float x1 = xp[kh * INW + 1];
            const float x2 = xp[kh * INW + 2];
#pragma unroll
            for (int t = 0; t < TCO; ++t) {
                const float* wt = wp + t * (CIN * 9) + kh * 3;
                acc[t] = fmaf(x0, wt[0], acc[t]);
                acc[t] = fmaf(x1, wt[1], acc[t]);
                acc[t] = fmaf(x2, wt[2], acc[t]);
            }
        }
    }
    if (valid) {
        const size_t ob = ((size_t)n * COUT + co0) * (OUTH * OUTW) + (size_t)oh * OUTW + ow;
#pragma unroll
        for (int t = 0; t < TCO; ++t)
            out[ob + (size_t)t * (OUTH * OUTW)] = acc[t];
    }
}

extern "C" void kernel_launch(void* const* d_in, const int* in_sizes, int n_in,
                              void* d_out, int out_size, void* d_ws, size_t ws_size,
                              hipStream_t stream) {
    const float* x    = (const float*)d_in[0];
    const float* w    = (const float*)d_in[1];
    const float* bias = (const float*)d_in[2];
    float* out        = (float*)d_out;

    const size_t xhwc_bytes = (size_t)NB * INH * INW * 64 * 2;   // 51,380,224
    const size_t ap_bytes   = (size_t)COUT * KTOT * 2;           // 147,456

    if (ws_size >= xhwc_bytes + ap_bytes) {
        unsigned short* xhwc = (unsigned short*)d_ws;
        unsigned short* apck = (unsigned short*)((char*)d_ws + xhwc_bytes);
        convert_x<<<dim3(INH, NB), 256, 0, stream>>>(x, xhwc);
        prepack_w<<<288, 256, 0, stream>>>(w, apck);
        conv_gemm<<<dim3(OUTH, NB), 256, 0, stream>>>(xhwc, apck, bias, out);
    } else {
        dim3 grid((NPIX + 255) / 256, COUT / TCO);
        conv_direct<<<grid, dim3(256), 0, stream>>>(x, w, bias, out);
    }
}